// Round 7
// baseline (167.341 us; speedup 1.0000x reference)
//
#include <hip/hip_runtime.h>
#include <hip/hip_bf16.h>

// EgoAttentionNetwork: B=8192, E=64, F_IN=7, D=64, H=4, HD=16. fp32 in/out.
// Round 13: DISCRIMINATING DIAGNOSTIC (correctness-preserving).
// Six theories eliminated (r7-r12). Data pattern: dispatch time ~linear in
// block count, invariant to per-wave work (316 vs 188 MFMA both 100K cy/wave),
// all pipes <25%. Three degenerate survivors:
//   T-A fixed per-wave latency | T-B workgroup dispatch rate | T-C CU contention
// Probe: split the real batches across 3 instantiations of the r12 kernel
// (NB = batches/wave), all correct, disjoint coverage; plus an empty kernel.
//   nop   : 8192 blocks  -> T-B: ~160us, else invisible
//   C NB=1: 4096 blocks (8/CU, 2 gens)  batches    0..4095
//   B NB=2: 1024 blocks (4/CU)          batches 4096..6143
//   A NB=4:  512 blocks (2/CU, same work/wave as r12's 42us) batches 6144..8191
// Signatures: T-A: A~=42 despite 1/4 grid; T-B: nop tops chart;
//             T-C: A~=30, B~=20, C~=40.

typedef __attribute__((ext_vector_type(8))) short short8;   // 8 bf16
typedef __attribute__((ext_vector_type(4))) short short4b;  // 4 bf16
typedef __attribute__((ext_vector_type(4))) float f32x4;

#define SY 72          // u16 row stride for LDS matrix buffers

// wave-local LDS fence: order DS ops at compile time, drain LDS counter only.
#define LDS_FENCE() asm volatile("s_waitcnt lgkmcnt(0)" ::: "memory")

// ws offsets in u16 units (total 33792 u16 = 67584 B)
#define WS_G    0      // [256][64]  G[(h*64+f)][j]
#define WS_EGW0 16384  // [64][8]    ego_w0^T (k<7 real, k=7 zero)
#define WS_EGW1 16896  // [64][64]   ego_w1^T
#define WS_WVT  20992  // [64][64]   Wv^T
#define WS_WCT  25088  // [64][64]   Wc^T
#define WS_W0T  29184  // [64][8]    oth_w0^T
#define WS_W1T  29696  // [64][64]   oth_w1^T

__device__ __forceinline__ short f2bs(float x) {
    __hip_bfloat16 h = __float2bfloat16(x);
    return __builtin_bit_cast(short, h);
}
__device__ __forceinline__ unsigned short f2u(float x) {
    __hip_bfloat16 h = __float2bfloat16(x);
    return __builtin_bit_cast(unsigned short, h);
}
__device__ __forceinline__ short8 ldws8(const unsigned short* p) {
    return *(const short8*)p;   // 16B-aligned -> global_load_dwordx4
}

__global__ void nop_kernel(float* sink) {
    if (sink != nullptr) sink[threadIdx.x] = 0.f;   // never taken (launched w/ null)
}

__global__ void pack_ws(const float* __restrict__ ego_w0, const float* __restrict__ ego_w1,
                        const float* __restrict__ oth_w0, const float* __restrict__ oth_w1,
                        const float* __restrict__ Wk, const float* __restrict__ Wv,
                        const float* __restrict__ Wq, const float* __restrict__ Wc,
                        unsigned short* __restrict__ ws) {
    const int blk = blockIdx.x, t = threadIdx.x;
    if (blk < 256) {
        // G[n=(h*64+f)][j] = sum_d Wq[j][16h+d] * Wk[f][16h+d]
        const int n = blk, h = n >> 6, f = n & 63, j = t;
        float a = 0.f;
#pragma unroll
        for (int d = 0; d < 16; ++d)
            a = fmaf(Wq[j * 64 + h * 16 + d], Wk[f * 64 + h * 16 + d], a);
        ws[WS_G + n * 64 + j] = f2u(a);
    } else {
        const int n = blk - 256, k = t;    // n = output col, k = contraction idx
        ws[WS_EGW1 + n * 64 + k] = f2u(ego_w1[k * 64 + n]);
        ws[WS_WVT  + n * 64 + k] = f2u(Wv[k * 64 + n]);
        ws[WS_WCT  + n * 64 + k] = f2u(Wc[k * 64 + n]);
        ws[WS_W1T  + n * 64 + k] = f2u(oth_w1[k * 64 + n]);
        if (k < 8) {
            ws[WS_EGW0 + n * 8 + k] = (k < 7) ? f2u(ego_w0[k * 64 + n]) : 0;
            ws[WS_W0T  + n * 8 + k] = (k < 7) ? f2u(oth_w0[k * 64 + n]) : 0;
        }
    }
}

template<int NB>
__global__ __launch_bounds__(64, 2)
void ego_attn_kernel(const float* __restrict__ x,
                     const float* __restrict__ ego_b0, const float* __restrict__ ego_b1,
                     const float* __restrict__ oth_b0, const float* __restrict__ oth_b1,
                     const unsigned short* __restrict__ ws,
                     float* __restrict__ out, int batchBase)
{
    __shared__ __align__(16) short hy[64 * SY];    // H/Y; also chainbuf + ob alias rows 0-3
    __shared__ __align__(16) short kqb[16 * SY];   // row b*4+h : kq[b][h][f]*0.25
    __shared__ __align__(16) short pa[4 * SY];     // P[h][e], 4 real rows
    __shared__ __align__(16) short py[16 * SY];    // row h*4+b : pY[b][h][f]
    __shared__ __align__(16) short xld[4 * 64 * 8];// x rows bf16 (7 + pad), per batch
    __shared__ __align__(16) float egf[4 * 64];    // egoR f32, row = batch
    __shared__ unsigned long long mball[4];        // ballot mask per batch

    const int lane = threadIdx.x;
    const int lg = lane >> 4, ln = lane & 15;
    const int gb = batchBase + blockIdx.x * NB;    // NB batches per wave
    const short8 z8 = {0, 0, 0, 0, 0, 0, 0, 0};

    // ---- persistent weight frags (16B vector loads from ws) ----
    short8 w0f[4], w1f[2][4];
#pragma unroll
    for (int ct = 0; ct < 4; ++ct)
        w0f[ct] = (lg == 0) ? ldws8(ws + WS_W0T + (ct * 16 + ln) * 8) : z8;
#pragma unroll
    for (int kc = 0; kc < 2; ++kc)
#pragma unroll
        for (int ct = 0; ct < 4; ++ct)
            w1f[kc][ct] = ldws8(ws + WS_W1T + (ct * 16 + ln) * 64 + kc * 32 + lg * 8);
    float b0v[4], b1v[4], eb0v[4], eb1v[4];
#pragma unroll
    for (int ct = 0; ct < 4; ++ct) {
        b0v[ct]  = oth_b0[ct * 16 + ln];
        b1v[ct]  = oth_b1[ct * 16 + ln];
        eb0v[ct] = ego_b0[ct * 16 + ln];
        eb1v[ct] = ego_b1[ct * 16 + ln];
    }

    // ---- prefetch: x rows -> xld (bf16, slot7=0), ballots -> mball ----
#pragma unroll
    for (int i = 0; i < NB; ++i) {
        const float* xr = x + (size_t)(gb + i) * 448 + lane * 7;   // lane = e
        const float v0 = xr[0];
        const unsigned long long mb = __ballot(v0 < 0.5f);
        if (lane == 0) mball[i] = mb;
        short8 v;
        v[0] = f2bs(v0);
#pragma unroll
        for (int k = 1; k < 7; ++k) v[k] = f2bs(xr[k]);
        v[7] = 0;
        *(short8*)&xld[((i << 6) | lane) * 8] = v;
    }
    LDS_FENCE();

    // ================= chain: egoL1 -> egoL2 -> KQ ==========================
    short8 xea;                                    // A[m=b][k<7] = x_b row 0
    {
        const short8 t = *(const short8*)&xld[((ln & 3) << 6) * 8];
        xea = (lg == 0 && ln < NB) ? t : z8;
    }
#pragma unroll
    for (int ct = 0; ct < 4; ++ct) {              // Hego = relu(x0 @ ego_w0 + b0)
        const short8 bfr = (lg == 0) ? ldws8(ws + WS_EGW0 + (ct * 16 + ln) * 8) : z8;
        f32x4 c = {eb0v[ct], eb0v[ct], eb0v[ct], eb0v[ct]};
        c = __builtin_amdgcn_mfma_f32_16x16x32_bf16(xea, bfr, c, 0, 0, 0);
        if (lg == 0) {
#pragma unroll
            for (int r = 0; r < 4; ++r)
                hy[r * SY + ct * 16 + ln] = f2bs(fmaxf(c[r], 0.f));   // chainbuf alias
        }
    }
    LDS_FENCE();
    short8 ha[2];
#pragma unroll
    for (int kc = 0; kc < 2; ++kc)
        ha[kc] = *(const short8*)&hy[(ln & 3) * SY + kc * 32 + lg * 8];
    LDS_FENCE();
#pragma unroll
    for (int ct = 0; ct < 4; ++ct) {              // Ego = relu(Hego @ ego_w1 + b1)
        f32x4 c = {eb1v[ct], eb1v[ct], eb1v[ct], eb1v[ct]};
#pragma unroll
        for (int kc = 0; kc < 2; ++kc) {
            const short8 bfr = ldws8(ws + WS_EGW1 + (ct * 16 + ln) * 64 + kc * 32 + lg * 8);
            c = __builtin_amdgcn_mfma_f32_16x16x32_bf16(ha[kc], bfr, c, 0, 0, 0);
        }
        if (lg == 0) {
#pragma unroll
            for (int r = 0; r < 4; ++r) {
                const float e = fmaxf(c[r], 0.f);
                egf[r * 64 + ct * 16 + ln] = e;                 // f32 for residual
                hy[r * SY + ct * 16 + ln] = f2bs(e);            // bf16 for ea
            }
        }
    }
    LDS_FENCE();
    short8 ea[2];
#pragma unroll
    for (int kc = 0; kc < 2; ++kc)
        ea[kc] = *(const short8*)&hy[(ln & 3) * SY + kc * 32 + lg * 8];

    // KQ[b][n=(h*64+f)] = sum_j Ego[b][j] G[n][j]; fold 0.25 score scale here
#pragma unroll 4
    for (int ctg = 0; ctg < 16; ++ctg) {
        f32x4 c = {0.f, 0.f, 0.f, 0.f};
#pragma unroll
        for (int kc = 0; kc < 2; ++kc) {
            const short8 bfr = ldws8(ws + WS_G + (ctg * 16 + ln) * 64 + kc * 32 + lg * 8);
            c = __builtin_amdgcn_mfma_f32_16x16x32_bf16(ea[kc], bfr, c, 0, 0, 0);
        }
        if (lg == 0) {
            const int h = ctg >> 2, fc = (ctg & 3) * 16 + ln;
#pragma unroll
            for (int r = 0; r < 4; ++r)
                kqb[(r * 4 + h) * SY + fc] = f2bs(c[r] * 0.25f);
        }
    }
    LDS_FENCE();

    // ============ per-batch body (ROLLED: appears once in code) =============
#pragma unroll 1
    for (int i = 0; i < NB; ++i) {
        // A-frags for this batch from xld (broadcast reads, zero for lg>0)
        short8 xa[4];
#pragma unroll
        for (int mt = 0; mt < 4; ++mt) {
            const short8 t = *(const short8*)&xld[((i << 6) | (mt * 16 + ln)) * 8];
            xa[mt] = (lg == 0) ? t : z8;
        }
        const unsigned long long mb = mball[i];

        // P1: H = relu(X @ W0 + b0)
#pragma unroll
        for (int mt = 0; mt < 4; ++mt)
#pragma unroll
            for (int ct = 0; ct < 4; ++ct) {
                f32x4 c = {b0v[ct], b0v[ct], b0v[ct], b0v[ct]};
                c = __builtin_amdgcn_mfma_f32_16x16x32_bf16(xa[mt], w0f[ct], c, 0, 0, 0);
#pragma unroll
                for (int r = 0; r < 4; ++r)
                    hy[(mt * 16 + lg * 4 + r) * SY + ct * 16 + ln] = f2bs(fmaxf(c[r], 0.f));
            }
        LDS_FENCE();
        short8 a2[4][2];
#pragma unroll
        for (int mt = 0; mt < 4; ++mt)
#pragma unroll
            for (int kc = 0; kc < 2; ++kc)
                a2[mt][kc] = *(const short8*)&hy[(mt * 16 + ln) * SY + kc * 32 + lg * 8];
        LDS_FENCE();
        // P2: Y = relu(H @ W1 + b1); then row 0 <- ego_i (from egf)
#pragma unroll
        for (int ct = 0; ct < 4; ++ct)
#pragma unroll
            for (int mt = 0; mt < 4; ++mt) {
                f32x4 c = {b1v[ct], b1v[ct], b1v[ct], b1v[ct]};
                c = __builtin_amdgcn_mfma_f32_16x16x32_bf16(a2[mt][0], w1f[0][ct], c, 0, 0, 0);
                c = __builtin_amdgcn_mfma_f32_16x16x32_bf16(a2[mt][1], w1f[1][ct], c, 0, 0, 0);
#pragma unroll
                for (int r = 0; r < 4; ++r)
                    hy[(mt * 16 + lg * 4 + r) * SY + ct * 16 + ln] = f2bs(fmaxf(c[r], 0.f));
            }
        if (lg == 0) {
#pragma unroll
            for (int ct = 0; ct < 4; ++ct)
                hy[ct * 16 + ln] = f2bs(egf[i * 64 + ct * 16 + ln]);  // Y row 0 = ego_i
        }
        LDS_FENCE();
        // S = Y @ kq_i^T (n=h, cols>=4 copies); softmax per head (h = ln&3)
        short8 kb[2];
#pragma unroll
        for (int kc = 0; kc < 2; ++kc)
            kb[kc] = *(const short8*)&kqb[(i * 4 + (ln & 3)) * SY + kc * 32 + lg * 8];

        float sv[16];
        float m = -3e38f;
#pragma unroll
        for (int mt = 0; mt < 4; ++mt) {
            const short8 ya0 = *(const short8*)&hy[(mt * 16 + ln) * SY + 0 * 32 + lg * 8];
            const short8 ya1 = *(const short8*)&hy[(mt * 16 + ln) * SY + 1 * 32 + lg * 8];
            f32x4 c = {0.f, 0.f, 0.f, 0.f};
            c = __builtin_amdgcn_mfma_f32_16x16x32_bf16(ya0, kb[0], c, 0, 0, 0);
            c = __builtin_amdgcn_mfma_f32_16x16x32_bf16(ya1, kb[1], c, 0, 0, 0);
#pragma unroll
            for (int r = 0; r < 4; ++r) {
                float s = c[r];                    // 0.25 folded into kqb
                if ((mb >> (mt * 16 + lg * 4 + r)) & 1ull) s = -1e9f;
                sv[mt * 4 + r] = s;
                m = fmaxf(m, s);
            }
        }
        m = fmaxf(m, __shfl_xor(m, 16));
        m = fmaxf(m, __shfl_xor(m, 32));
        float sum = 0.f;
#pragma unroll
        for (int k = 0; k < 16; ++k) { sv[k] = __expf(sv[k] - m); sum += sv[k]; }
        sum += __shfl_xor(sum, 16);
        sum += __shfl_xor(sum, 32);
        const float inv = 1.f / sum;
        if (ln < 4) {                              // 4 real P rows (h = ln)
#pragma unroll
            for (int mt = 0; mt < 4; ++mt) {
                short4b pk;
#pragma unroll
                for (int r = 0; r < 4; ++r) pk[r] = f2bs(sv[mt * 4 + r] * inv);
                *(short4b*)&pa[ln * SY + mt * 16 + lg * 4] = pk;
            }
        }
        LDS_FENCE();
        // pY = P @ Y (A rows replicated via ln&3)
        short8 pf[2];
#pragma unroll
        for (int kc = 0; kc < 2; ++kc)
            pf[kc] = *(const short8*)&pa[(ln & 3) * SY + kc * 32 + lg * 8];
#pragma unroll
        for (int ct = 0; ct < 4; ++ct) {
            f32x4 c = {0.f, 0.f, 0.f, 0.f};
#pragma unroll
            for (int kc = 0; kc < 2; ++kc) {
                short8 yv;
#pragma unroll
                for (int j = 0; j < 8; ++j)
                    yv[j] = hy[(kc * 32 + lg * 8 + j) * SY + ct * 16 + ln];
                c = __builtin_amdgcn_mfma_f32_16x16x32_bf16(pf[kc], yv, c, 0, 0, 0);
            }
            if (lg == 0) {
#pragma unroll
                for (int r = 0; r < 4; ++r)
                    py[(r * 4 + i) * SY + ct * 16 + ln] = f2bs(c[r]);   // row h*4+b
            }
        }
        LDS_FENCE();
    }

    // ================= tail: o64 = pY @ Wv (head-sliced), result ============
#pragma unroll
    for (int ct = 0; ct < 4; ++ct) {              // ct = head h; cols 16h..16h+16
        short8 af[2];
#pragma unroll
        for (int kc = 0; kc < 2; ++kc)
            af[kc] = *(const short8*)&py[(ct * 4 + (ln & 3)) * SY + kc * 32 + lg * 8];
        f32x4 c = {0.f, 0.f, 0.f, 0.f};
#pragma unroll
        for (int kc = 0; kc < 2; ++kc) {
            const short8 bfr = ldws8(ws + WS_WVT + (ct * 16 + ln) * 64 + kc * 32 + lg * 8);
            c = __builtin_amdgcn_mfma_f32_16x16x32_bf16(af[kc], bfr, c, 0, 0, 0);
        }
        if (lg == 0) {
#pragma unroll
            for (int r = 0; r < 4; ++r)
                hy[r * SY + ct * 16 + ln] = f2bs(c[r]);         // ob alias rows b
        }
    }
    LDS_FENCE();
    short8 oa[2];
#pragma unroll
    for (int kc = 0; kc < 2; ++kc)
        oa[kc] = *(const short8*)&hy[(ln & 3) * SY + kc * 32 + lg * 8];
#pragma unroll
    for (int ct = 0; ct < 4; ++ct) {              // result = o64 @ Wc + ego, *0.5
        f32x4 c = {0.f, 0.f, 0.f, 0.f};
#pragma unroll
        for (int kc = 0; kc < 2; ++kc) {
            const short8 bfr = ldws8(ws + WS_WCT + (ct * 16 + ln) * 64 + kc * 32 + lg * 8);
            c = __builtin_amdgcn_mfma_f32_16x16x32_bf16(oa[kc], bfr, c, 0, 0, 0);
        }
        if (lg == 0) {
#pragma unroll
            for (int r = 0; r < 4; ++r)
                if (r < NB)
                    out[(size_t)(gb + r) * 64 + ct * 16 + ln] =
                        (c[r] + egf[r * 64 + ct * 16 + ln]) * 0.5f;
        }
    }
}

extern "C" void kernel_launch(void* const* d_in, const int* in_sizes, int n_in,
                              void* d_out, int out_size, void* d_ws, size_t ws_size,
                              hipStream_t stream) {
    const float* x      = (const float*)d_in[0];
    const float* ego_w0 = (const float*)d_in[1];
    const float* ego_b0 = (const float*)d_in[2];
    const float* ego_w1 = (const float*)d_in[3];
    const float* ego_b1 = (const float*)d_in[4];
    const float* oth_w0 = (const float*)d_in[5];
    const float* oth_b0 = (const float*)d_in[6];
    const float* oth_w1 = (const float*)d_in[7];
    const float* oth_b1 = (const float*)d_in[8];
    const float* Wk     = (const float*)d_in[9];
    const float* Wv     = (const float*)d_in[10];
    const float* Wq     = (const float*)d_in[11];
    const float* Wc     = (const float*)d_in[12];

    unsigned short* ws = (unsigned short*)d_ws;   // needs 67584 B
    pack_ws<<<320, 64, 0, stream>>>(ego_w0, ego_w1, oth_w0, oth_w1,
                                    Wk, Wv, Wq, Wc, ws);

    // ---- T-B probe: empty kernel, 8192 workgroups ----
    nop_kernel<<<8192, 64, 0, stream>>>(nullptr);

    // ---- real work, split across NB variants (disjoint batch coverage) ----
    float* out = (float*)d_out;
    ego_attn_kernel<1><<<4096, 64, 0, stream>>>(   // batches 0..4095
        x, ego_b0, ego_b1, oth_b0, oth_b1, ws, out, 0);
    ego_attn_kernel<2><<<1024, 64, 0, stream>>>(   // batches 4096..6143
        x, ego_b0, ego_b1, oth_b0, oth_b1, ws, out, 4096);
    ego_attn_kernel<4><<<512, 64, 0, stream>>>(    // batches 6144..8191
        x, ego_b0, ego_b1, oth_b0, oth_b1, ws, out, 6144);
}

// Round 9
// 125.878 us; speedup vs baseline: 1.3294x; 1.3294x over previous
//
#include <hip/hip_runtime.h>
#include <hip/hip_bf16.h>

// EgoAttentionNetwork: B=8192, E=64, F_IN=7, D=64, H=4, HD=16. fp32 in/out.
// Round 15 (= r14 resubmit; r14 bench was an infra failure, no data).
// Validated cost model T = 4.3ns*blocks + ~32cy/CU*bundles (r13 probe:
// nop@8192<43.6us; NB=1@4096=43.6us 2gens; fits r12=8.8+33us and explains
// r10: dual-P2 grew total bundles 40% -> slower).
// Attack both terms without growing either:
//  (1) NB=8, grid 1024: block term 8.8->4.4us, chain amortized over 8.
//  (2) Packed C-writes via SWAPPED single-orientation P1/P2/egoL1/KQ:
//      C-frag holds 4 consecutive rows per lane -> one ds_write_b64 vs 4
//      ds_write_b16. NO extra MFMAs (same frags reused as A<->B: both frag
//      layouts are k-contiguous). All consumers keep reading [e][d] layout
//      (a2/ya/yv/kb identical to r12). SY=72 kept (no r10 conflicts).
//      ~-770 LDS instrs/wave (~25% of LDS traffic).
// LDS 29312B -> 5 blocks/CU >= 4 supplied by grid. MFMA count unchanged.

typedef __attribute__((ext_vector_type(8))) short short8;   // 8 bf16
typedef __attribute__((ext_vector_type(4))) short short4b;  // 4 bf16
typedef __attribute__((ext_vector_type(4))) float f32x4;

#define SY 72          // u16 row stride for LDS matrix buffers

// wave-local LDS fence: order DS ops at compile time, drain LDS counter only.
#define LDS_FENCE() asm volatile("s_waitcnt lgkmcnt(0)" ::: "memory")

// ws offsets in u16 units (total 33792 u16 = 67584 B)
#define WS_G    0      // [256][64]  G[(h*64+f)][j]
#define WS_EGW0 16384  // [64][8]    ego_w0^T (k<7 real, k=7 zero)
#define WS_EGW1 16896  // [64][64]   ego_w1^T
#define WS_WVT  20992  // [64][64]   Wv^T
#define WS_WCT  25088  // [64][64]   Wc^T
#define WS_W0T  29184  // [64][8]    oth_w0^T
#define WS_W1T  29696  // [64][64]   oth_w1^T

__device__ __forceinline__ short f2bs(float x) {
    __hip_bfloat16 h = __float2bfloat16(x);
    return __builtin_bit_cast(short, h);
}
__device__ __forceinline__ unsigned short f2u(float x) {
    __hip_bfloat16 h = __float2bfloat16(x);
    return __builtin_bit_cast(unsigned short, h);
}
__device__ __forceinline__ short8 ldws8(const unsigned short* p) {
    return *(const short8*)p;   // 16B-aligned -> global_load_dwordx4
}
__device__ __forceinline__ short4b pk4r(f32x4 c) {      // relu + pack
    short4b p;
#pragma unroll
    for (int r = 0; r < 4; ++r) p[r] = f2bs(fmaxf(c[r], 0.f));
    return p;
}
__device__ __forceinline__ short4b pk4s(f32x4 c, float s) {  // scale + pack
    short4b p;
#pragma unroll
    for (int r = 0; r < 4; ++r) p[r] = f2bs(c[r] * s);
    return p;
}

__global__ void pack_ws(const float* __restrict__ ego_w0, const float* __restrict__ ego_w1,
                        const float* __restrict__ oth_w0, const float* __restrict__ oth_w1,
                        const float* __restrict__ Wk, const float* __restrict__ Wv,
                        const float* __restrict__ Wq, const float* __restrict__ Wc,
                        unsigned short* __restrict__ ws) {
    const int blk = blockIdx.x, t = threadIdx.x;
    if (blk < 256) {
        // G[n=(h*64+f)][j] = sum_d Wq[j][16h+d] * Wk[f][16h+d]
        const int n = blk, h = n >> 6, f = n & 63, j = t;
        float a = 0.f;
#pragma unroll
        for (int d = 0; d < 16; ++d)
            a = fmaf(Wq[j * 64 + h * 16 + d], Wk[f * 64 + h * 16 + d], a);
        ws[WS_G + n * 64 + j] = f2u(a);
    } else {
        const int n = blk - 256, k = t;    // n = output col, k = contraction idx
        ws[WS_EGW1 + n * 64 + k] = f2u(ego_w1[k * 64 + n]);
        ws[WS_WVT  + n * 64 + k] = f2u(Wv[k * 64 + n]);
        ws[WS_WCT  + n * 64 + k] = f2u(Wc[k * 64 + n]);
        ws[WS_W1T  + n * 64 + k] = f2u(oth_w1[k * 64 + n]);
        if (k < 8) {
            ws[WS_EGW0 + n * 8 + k] = (k < 7) ? f2u(ego_w0[k * 64 + n]) : 0;
            ws[WS_W0T  + n * 8 + k] = (k < 7) ? f2u(oth_w0[k * 64 + n]) : 0;
        }
    }
}

__global__ __launch_bounds__(64, 2)
void ego_attn_kernel(const float* __restrict__ x,
                     const float* __restrict__ ego_b0, const float* __restrict__ ego_b1,
                     const float* __restrict__ oth_b0, const float* __restrict__ oth_b1,
                     const unsigned short* __restrict__ ws,
                     float* __restrict__ out)
{
    __shared__ __align__(16) short hy[64 * SY];    // [e][d]; alias chainbuf/ob rows 0-7
    __shared__ __align__(16) short kqb[32 * SY];   // row b*4+h : kq[b][h][f]*0.25
    __shared__ __align__(16) short pa[4 * SY];     // P[h][e], 4 real rows
    __shared__ __align__(16) short py[32 * SY];    // row h*8+b : pY[b][h][f]
    __shared__ __align__(16) short xld[8 * 64 * 8];// x rows bf16 (7 + pad), per batch
    __shared__ __align__(16) float egf[8 * 64];    // egoR f32, row = batch
    __shared__ unsigned long long mball[8];        // ballot mask per batch

    const int lane = threadIdx.x;
    const int lg = lane >> 4, ln = lane & 15;
    const int gb = blockIdx.x * 8;                 // 8 batches per wave
    const short8 z8 = {0, 0, 0, 0, 0, 0, 0, 0};

    // ---- persistent weight frags (16B vector loads from ws) ----
    short8 w0f[4], w1f[2][4];                      // k-contiguous: valid as A or B
#pragma unroll
    for (int t = 0; t < 4; ++t)
        w0f[t] = (lg == 0) ? ldws8(ws + WS_W0T + (t * 16 + ln) * 8) : z8;
#pragma unroll
    for (int kc = 0; kc < 2; ++kc)
#pragma unroll
        for (int t = 0; t < 4; ++t)
            w1f[kc][t] = ldws8(ws + WS_W1T + (t * 16 + ln) * 64 + kc * 32 + lg * 8);
    float eb1v[4];
#pragma unroll
    for (int t = 0; t < 4; ++t) eb1v[t] = ego_b1[t * 16 + ln];

    // ---- prefetch: x rows -> xld (bf16, slot7=0), ballots -> mball ----
#pragma unroll
    for (int i = 0; i < 8; ++i) {
        const float* xr = x + (size_t)(gb + i) * 448 + lane * 7;   // lane = e
        const float v0 = xr[0];
        const unsigned long long mb = __ballot(v0 < 0.5f);
        if (lane == 0) mball[i] = mb;
        short8 v;
        v[0] = f2bs(v0);
#pragma unroll
        for (int k = 1; k < 7; ++k) v[k] = f2bs(xr[k]);
        v[7] = 0;
        *(short8*)&xld[((i << 6) | lane) * 8] = v;
    }
    LDS_FENCE();

    // ================= chain: egoL1 -> egoL2 -> KQ ==========================
    short8 xea;                                    // B-frag: n=b (ln<8), k<7 (lg==0)
    {
        const short8 t = *(const short8*)&xld[((ln & 7) << 6) * 8];
        xea = (lg == 0 && ln < 8) ? t : z8;
    }
    // egoL1 SWAPPED: C = Hego^T (m=d, n=b) -> packed b64 into hy[b][d] rows 0-7
#pragma unroll
    for (int dt = 0; dt < 4; ++dt) {
        const short8 af = (lg == 0) ? ldws8(ws + WS_EGW0 + (dt * 16 + ln) * 8) : z8;
        const float4 bq = *(const float4*)&ego_b0[dt * 16 + lg * 4];
        f32x4 c = {bq.x, bq.y, bq.z, bq.w};
        c = __builtin_amdgcn_mfma_f32_16x16x32_bf16(af, xea, c, 0, 0, 0);
        if (ln < 8)
            *(short4b*)&hy[ln * SY + dt * 16 + lg * 4] = pk4r(c);
    }
    LDS_FENCE();
    short8 ha[2];                                  // A-frag m=b (ln&7), k=d contig
#pragma unroll
    for (int kc = 0; kc < 2; ++kc)
        ha[kc] = *(const short8*)&hy[(ln & 7) * SY + kc * 32 + lg * 8];
    LDS_FENCE();
    // egoL2 unswapped: C rows = b (lg<2 real), cols = d
#pragma unroll
    for (int ct = 0; ct < 4; ++ct) {
        f32x4 c = {eb1v[ct], eb1v[ct], eb1v[ct], eb1v[ct]};
#pragma unroll
        for (int kc = 0; kc < 2; ++kc) {
            const short8 bfr = ldws8(ws + WS_EGW1 + (ct * 16 + ln) * 64 + kc * 32 + lg * 8);
            c = __builtin_amdgcn_mfma_f32_16x16x32_bf16(ha[kc], bfr, c, 0, 0, 0);
        }
        if (lg < 2) {
#pragma unroll
            for (int r = 0; r < 4; ++r) {
                const float e = fmaxf(c[r], 0.f);
                egf[(lg * 4 + r) * 64 + ct * 16 + ln] = e;          // f32 residual
                hy[(lg * 4 + r) * SY + ct * 16 + ln] = f2bs(e);     // bf16 for ea
            }
        }
    }
    LDS_FENCE();
    short8 ea[2];                                  // B-frag n=b (ln&7), k=j contig
#pragma unroll
    for (int kc = 0; kc < 2; ++kc)
        ea[kc] = *(const short8*)&hy[(ln & 7) * SY + kc * 32 + lg * 8];

    // KQ SWAPPED: C (m=(h,f), n=b) -> packed b64 into kqb[b*4+h][f]; fold 0.25
#pragma unroll 4
    for (int ctg = 0; ctg < 16; ++ctg) {
        f32x4 c = {0.f, 0.f, 0.f, 0.f};
#pragma unroll
        for (int kc = 0; kc < 2; ++kc) {
            const short8 g = ldws8(ws + WS_G + (ctg * 16 + ln) * 64 + kc * 32 + lg * 8);
            c = __builtin_amdgcn_mfma_f32_16x16x32_bf16(g, ea[kc], c, 0, 0, 0);
        }
        if (ln < 8)    // f = (ctg&3)*16 + lg*4 + r, h = ctg>>2, b = ln
            *(short4b*)&kqb[(ln * 4 + (ctg >> 2)) * SY + (ctg & 3) * 16 + lg * 4] =
                pk4s(c, 0.25f);
    }
    LDS_FENCE();

    // ============ per-batch body (ROLLED: appears once in code) =============
#pragma unroll 1
    for (int i = 0; i < 8; ++i) {
        short8 xa[4];                              // B-frag n=e, k<7 (lg==0)
#pragma unroll
        for (int mt = 0; mt < 4; ++mt) {
            const short8 t = *(const short8*)&xld[((i << 6) | (mt * 16 + ln)) * 8];
            xa[mt] = (lg == 0) ? t : z8;
        }
        const unsigned long long mb = mball[i];

        // P1 SWAPPED: C = H^T (m=d, n=e) -> packed b64 into hy[e][d]
#pragma unroll
        for (int dt = 0; dt < 4; ++dt) {
            const float4 bq = *(const float4*)&oth_b0[dt * 16 + lg * 4];
#pragma unroll
            for (int et = 0; et < 4; ++et) {
                f32x4 c = {bq.x, bq.y, bq.z, bq.w};
                c = __builtin_amdgcn_mfma_f32_16x16x32_bf16(w0f[dt], xa[et], c, 0, 0, 0);
                *(short4b*)&hy[(et * 16 + ln) * SY + dt * 16 + lg * 4] = pk4r(c);
            }
        }
        LDS_FENCE();
        short8 a2[4][2];                           // H[e][d] frags (A or B use)
#pragma unroll
        for (int mt = 0; mt < 4; ++mt)
#pragma unroll
            for (int kc = 0; kc < 2; ++kc)
                a2[mt][kc] = *(const short8*)&hy[(mt * 16 + ln) * SY + kc * 32 + lg * 8];
        LDS_FENCE();
        // P2 SWAPPED: C = Y^T (m=dout, n=e) -> packed b64 into hy[e][d]
#pragma unroll
        for (int dt = 0; dt < 4; ++dt) {
            const float4 bq = *(const float4*)&oth_b1[dt * 16 + lg * 4];
#pragma unroll
            for (int et = 0; et < 4; ++et) {
                f32x4 c = {bq.x, bq.y, bq.z, bq.w};
                c = __builtin_amdgcn_mfma_f32_16x16x32_bf16(w1f[0][dt], a2[et][0], c, 0, 0, 0);
                c = __builtin_amdgcn_mfma_f32_16x16x32_bf16(w1f[1][dt], a2[et][1], c, 0, 0, 0);
                *(short4b*)&hy[(et * 16 + ln) * SY + dt * 16 + lg * 4] = pk4r(c);
            }
        }
        if (lg == 0) {
#pragma unroll
            for (int ct = 0; ct < 4; ++ct)
                hy[ct * 16 + ln] = f2bs(egf[i * 64 + ct * 16 + ln]);  // Y row 0 = ego_i
        }
        LDS_FENCE();
        // S = Y @ kq_i^T (n=h, cols>=4 copies); softmax per head (h = ln&3)
        short8 kb[2];
#pragma unroll
        for (int kc = 0; kc < 2; ++kc)
            kb[kc] = *(const short8*)&kqb[(i * 4 + (ln & 3)) * SY + kc * 32 + lg * 8];

        float sv[16];
        float m = -3e38f;
#pragma unroll
        for (int mt = 0; mt < 4; ++mt) {
            const short8 ya0 = *(const short8*)&hy[(mt * 16 + ln) * SY + 0 * 32 + lg * 8];
            const short8 ya1 = *(const short8*)&hy[(mt * 16 + ln) * SY + 1 * 32 + lg * 8];
            f32x4 c = {0.f, 0.f, 0.f, 0.f};
            c = __builtin_amdgcn_mfma_f32_16x16x32_bf16(ya0, kb[0], c, 0, 0, 0);
            c = __builtin_amdgcn_mfma_f32_16x16x32_bf16(ya1, kb[1], c, 0, 0, 0);
#pragma unroll
            for (int r = 0; r < 4; ++r) {
                float s = c[r];                    // 0.25 folded into kqb
                if ((mb >> (mt * 16 + lg * 4 + r)) & 1ull) s = -1e9f;
                sv[mt * 4 + r] = s;
                m = fmaxf(m, s);
            }
        }
        m = fmaxf(m, __shfl_xor(m, 16));
        m = fmaxf(m, __shfl_xor(m, 32));
        float sum = 0.f;
#pragma unroll
        for (int k = 0; k < 16; ++k) { sv[k] = __expf(sv[k] - m); sum += sv[k]; }
        sum += __shfl_xor(sum, 16);
        sum += __shfl_xor(sum, 32);
        const float inv = 1.f / sum;
        if (ln < 4) {                              // 4 real P rows (h = ln)
#pragma unroll
            for (int mt = 0; mt < 4; ++mt) {
                short4b pk;
#pragma unroll
                for (int r = 0; r < 4; ++r) pk[r] = f2bs(sv[mt * 4 + r] * inv);
                *(short4b*)&pa[ln * SY + mt * 16 + lg * 4] = pk;
            }
        }
        LDS_FENCE();
        // pY = P @ Y (A rows replicated via ln&3); write py row h*8+i
        short8 pf[2];
#pragma unroll
        for (int kc = 0; kc < 2; ++kc)
            pf[kc] = *(const short8*)&pa[(ln & 3) * SY + kc * 32 + lg * 8];
#pragma unroll
        for (int ct = 0; ct < 4; ++ct) {
            f32x4 c = {0.f, 0.f, 0.f, 0.f};
#pragma unroll
            for (int kc = 0; kc < 2; ++kc) {
                short8 yv;
#pragma unroll
                for (int j = 0; j < 8; ++j)
                    yv[j] = hy[(kc * 32 + lg * 8 + j) * SY + ct * 16 + ln];
                c = __builtin_amdgcn_mfma_f32_16x16x32_bf16(pf[kc], yv, c, 0, 0, 0);
            }
            if (lg == 0) {
#pragma unroll
                for (int r = 0; r < 4; ++r)
                    py[(r * 8 + i) * SY + ct * 16 + ln] = f2bs(c[r]);
            }
        }
        LDS_FENCE();
    }

    // ================= tail: o64 = pY @ Wv (head-sliced), result ============
#pragma unroll
    for (int ct = 0; ct < 4; ++ct) {              // ct = head h; cols 16h..16h+16
        short8 af[2];                              // A-frag m=b (ln&7)
#pragma unroll
        for (int kc = 0; kc < 2; ++kc)
            af[kc] = *(const short8*)&py[(ct * 8 + (ln & 7)) * SY + kc * 32 + lg * 8];
        f32x4 c = {0.f, 0.f, 0.f, 0.f};
#pragma unroll
        for (int kc = 0; kc < 2; ++kc) {
            const short8 bfr = ldws8(ws + WS_WVT + (ct * 16 + ln) * 64 + kc * 32 + lg * 8);
            c = __builtin_amdgcn_mfma_f32_16x16x32_bf16(af[kc], bfr, c, 0, 0, 0);
        }
        if (lg < 2) {                              // ob rows b = lg*4+r (hy alias)
#pragma unroll
            for (int r = 0; r < 4; ++r)
                hy[(lg * 4 + r) * SY + ct * 16 + ln] = f2bs(c[r]);
        }
    }
    LDS_FENCE();
    short8 oa[2];                                  // A-frag m=b (ln&7)
#pragma unroll
    for (int kc = 0; kc < 2; ++kc)
        oa[kc] = *(const short8*)&hy[(ln & 7) * SY + kc * 32 + lg * 8];
#pragma unroll
    for (int ct = 0; ct < 4; ++ct) {              // result = o64 @ Wc + ego, *0.5
        f32x4 c = {0.f, 0.f, 0.f, 0.f};
#pragma unroll
        for (int kc = 0; kc < 2; ++kc) {
            const short8 bfr = ldws8(ws + WS_WCT + (ct * 16 + ln) * 64 + kc * 32 + lg * 8);
            c = __builtin_amdgcn_mfma_f32_16x16x32_bf16(oa[kc], bfr, c, 0, 0, 0);
        }
        if (lg < 2) {                              // rows b = lg*4+r (0..7)
#pragma unroll
            for (int r = 0; r < 4; ++r)
                out[(size_t)(gb + lg * 4 + r) * 64 + ct * 16 + ln] =
                    (c[r] + egf[(lg * 4 + r) * 64 + ct * 16 + ln]) * 0.5f;
        }
    }
}

extern "C" void kernel_launch(void* const* d_in, const int* in_sizes, int n_in,
                              void* d_out, int out_size, void* d_ws, size_t ws_size,
                              hipStream_t stream) {
    const float* x      = (const float*)d_in[0];
    const float* ego_w0 = (const float*)d_in[1];
    const float* ego_b0 = (const float*)d_in[2];
    const float* ego_w1 = (const float*)d_in[3];
    const float* ego_b1 = (const float*)d_in[4];
    const float* oth_w0 = (const float*)d_in[5];
    const float* oth_b0 = (const float*)d_in[6];
    const float* oth_w1 = (const float*)d_in[7];
    const float* oth_b1 = (const float*)d_in[8];
    const float* Wk     = (const float*)d_in[9];
    const float* Wv     = (const float*)d_in[10];
    const float* Wq     = (const float*)d_in[11];
    const float* Wc     = (const float*)d_in[12];

    unsigned short* ws = (unsigned short*)d_ws;   // needs 67584 B
    pack_ws<<<320, 64, 0, stream>>>(ego_w0, ego_w1, oth_w0, oth_w1,
                                    Wk, Wv, Wq, Wc, ws);
    ego_attn_kernel<<<1024, 64, 0, stream>>>(
        x, ego_b0, ego_b1, oth_b0, oth_b1, ws, (float*)d_out);
}